// Round 2
// baseline (246.709 us; speedup 1.0000x reference)
//
#include <hip/hip_runtime.h>
#include <hip/hip_bf16.h>

typedef __attribute__((ext_vector_type(8))) short s16x8;
typedef __attribute__((ext_vector_type(4))) float f32x4;

#define K_DIM 1024
#define I_DIM 4096
#define BM 256
#define BN 256
#define BK 64
#define NT (K_DIM / BK)  // 16 K-tiles

__device__ __forceinline__ unsigned short f2bf_bits(float v) {
    // exact for integers |v| <= 255
    return (unsigned short)(__builtin_bit_cast(unsigned int, v) >> 16);
}

__device__ __forceinline__ float fakeq_int(float x, float s, float zp) {
    float q = fminf(fmaxf(rintf(x / s) + zp, 0.0f), 255.0f);
    return q - zp;
}

// ---- quantize activations: fp32 [M*K] -> bf16 integer codes (q - zp)
__global__ void quant_x_kernel(const float* __restrict__ x, unsigned short* __restrict__ Aq,
                               const float* __restrict__ a_scale, const float* __restrict__ a_zero,
                               long long n) {
    long long i = ((long long)blockIdx.x * blockDim.x + threadIdx.x) * 4;
    if (i >= n) return;
    float s = a_scale[0];
    float zp = rintf(a_zero[0]);
    float4 v = *(const float4*)(x + i);
    ushort4 o;
    o.x = f2bf_bits(fakeq_int(v.x, s, zp));
    o.y = f2bf_bits(fakeq_int(v.y, s, zp));
    o.z = f2bf_bits(fakeq_int(v.z, s, zp));
    o.w = f2bf_bits(fakeq_int(v.w, s, zp));
    *(ushort4*)(Aq + i) = o;
}

// ---- quantize weights: per-row scale/zero
__global__ void quant_w_kernel(const float* __restrict__ w, unsigned short* __restrict__ Wq,
                               const float* __restrict__ w_scale, const float* __restrict__ w_zero,
                               long long n) {
    long long i = ((long long)blockIdx.x * blockDim.x + threadIdx.x) * 4;
    if (i >= n) return;
    long long row = i >> 10;  // K = 1024
    float s = w_scale[row];
    float zp = rintf(w_zero[row]);
    float4 v = *(const float4*)(w + i);
    ushort4 o;
    o.x = f2bf_bits(fakeq_int(v.x, s, zp));
    o.y = f2bf_bits(fakeq_int(v.y, s, zp));
    o.z = f2bf_bits(fakeq_int(v.z, s, zp));
    o.w = f2bf_bits(fakeq_int(v.w, s, zp));
    *(ushort4*)(Wq + i) = o;
}

#define GLL(SRC, DST)                                                         \
    __builtin_amdgcn_global_load_lds(                                         \
        (const __attribute__((address_space(1))) void*)(SRC),                 \
        (__attribute__((address_space(3))) void*)(DST), 16, 0, 0)

// stage chunk CC (64 rows x 64 k) of K-tile TT into buffer BB (linear dest,
// pre-swizzled source so that LDS row r holds its 16B k-slots permuted by r&7)
#define STA(TT, BB, CC) GLL(srcA[CC] + (TT) * BK, AsF + (BB) * (BM * BK) + (CC) * 4096 + wbase)
#define STB(TT, BB, CC) GLL(srcB[CC] + (TT) * BK, BsF + (BB) * (BN * BK) + (CC) * 4096 + wbase)

// ---- 256x256x64 8-phase GEMM (2 K-tiles per 8 phases), fused scale+bias+GELU
__global__ __launch_bounds__(512, 2) void gemm_gelu_kernel(
    const unsigned short* __restrict__ Aq,   // [M][K] bf16 integer codes
    const unsigned short* __restrict__ Wq,   // [I][K]
    const float* __restrict__ bias,
    const float* __restrict__ w_scale,
    const float* __restrict__ a_scale,
    float* __restrict__ out,                 // [M][I] fp32
    int M, int Ntiles) {
    __shared__ alignas(16) unsigned short AsF[2 * BM * BK];  // 64 KB
    __shared__ alignas(16) unsigned short BsF[2 * BN * BK];  // 64 KB

    // bijective XCD-aware swizzle
    int nwg = gridDim.x, bid = blockIdx.x;
    int xcd = bid & 7, lin = bid >> 3;
    int q8 = nwg >> 3, r8 = nwg & 7;
    int swz = (xcd < r8 ? xcd * (q8 + 1) : r8 * (q8 + 1) + (xcd - r8) * q8) + lin;
    int mt = swz / Ntiles, nt = swz % Ntiles;

    int tid = threadIdx.x;
    int wave = tid >> 6, lane = tid & 63;
    int wr = wave >> 2, wc = wave & 3;  // 2 (M) x 4 (N) waves, per-wave 128x64

    long long mrow0 = (long long)mt * BM;
    int ncol0 = nt * BN;

    // staging source pointers: thread t covers row (chunk*64 + t>>3), k-slot (t&7)^((t>>3)&7)
    int rsub = tid >> 3;
    int slotsrc = (tid & 7) ^ ((tid >> 3) & 7);
    const unsigned short* srcA[4];
    const unsigned short* srcB[4];
#pragma unroll
    for (int c = 0; c < 4; ++c) {
        long long ra = mrow0 + c * 64 + rsub;
        if (ra > (long long)M - 1) ra = M - 1;  // clamp: pad rows never stored
        srcA[c] = Aq + ra * K_DIM + slotsrc * 8;
        srcB[c] = Wq + ((long long)ncol0 + c * 64 + rsub) * K_DIM + slotsrc * 8;
    }
    int wbase = wave * 512;  // elements: wave's 1KB slice of each 8KB chunk

    // ds_read addressing: row = base + frag*16 + (lane&15); k-slot = ((lane>>4) + kk*4) ^ (lane&7)
    int s0 = (lane >> 4) ^ (lane & 7);
    int koffe0 = s0 * 8;         // elements (16B slots)
    int koffe1 = (s0 ^ 4) * 8;
    int arowb = wr * 128 + (lane & 15);
    int browb = wc * 64 + (lane & 15);

    f32x4 acc[8][4];
#pragma unroll
    for (int m = 0; m < 8; ++m)
#pragma unroll
        for (int n = 0; n < 4; ++n) acc[m][n] = (f32x4)0.0f;

    // prologue: tile0 full + tile1 {A0,A2,B0,B1}; leave tile1's 4 in flight
#pragma unroll
    for (int c = 0; c < 4; ++c) STA(0, 0, c);
#pragma unroll
    for (int c = 0; c < 4; ++c) STB(0, 0, c);
    STA(1, 1, 0);
    STA(1, 1, 2);
    STB(1, 1, 0);
    STB(1, 1, 1);
    asm volatile("s_waitcnt vmcnt(4)" ::: "memory");
    __builtin_amdgcn_s_barrier();

#pragma unroll 2
    for (int t = 0; t < NT; ++t) {
        const int b = t & 1, bn = b ^ 1;
        const int aB = b * (BM * BK), bB = b * (BN * BK);
        s16x8 af[4];
        s16x8 bfr[4][2];

        // ===== phase 0: mh=0, kk=0 — 8 ds_read; stage B{2,3}(t+1) =====
#pragma unroll
        for (int mi = 0; mi < 4; ++mi)
            af[mi] = *(const s16x8*)(AsF + aB + (arowb + mi * 16) * BK + koffe0);
#pragma unroll
        for (int n = 0; n < 4; ++n)
            bfr[n][0] = *(const s16x8*)(BsF + bB + (browb + n * 16) * BK + koffe0);
        if (t + 1 < NT) { STB(t + 1, bn, 2); STB(t + 1, bn, 3); }
        __builtin_amdgcn_s_barrier();
        asm volatile("s_waitcnt lgkmcnt(0)" ::: "memory");
        __builtin_amdgcn_sched_barrier(0);
        __builtin_amdgcn_s_setprio(1);
#pragma unroll
        for (int mi = 0; mi < 4; ++mi)
#pragma unroll
            for (int n = 0; n < 4; ++n)
                acc[mi][n] = __builtin_amdgcn_mfma_f32_16x16x32_bf16(af[mi], bfr[n][0], acc[mi][n], 0, 0, 0);
        __builtin_amdgcn_s_setprio(0);
        __builtin_amdgcn_s_barrier();

        // ===== phase 1: mh=0, kk=1 — 8 ds_read; stage A{1,3}(t+1) =====
#pragma unroll
        for (int mi = 0; mi < 4; ++mi)
            af[mi] = *(const s16x8*)(AsF + aB + (arowb + mi * 16) * BK + koffe1);
#pragma unroll
        for (int n = 0; n < 4; ++n)
            bfr[n][1] = *(const s16x8*)(BsF + bB + (browb + n * 16) * BK + koffe1);
        if (t + 1 < NT) { STA(t + 1, bn, 1); STA(t + 1, bn, 3); }
        __builtin_amdgcn_s_barrier();
        asm volatile("s_waitcnt lgkmcnt(0)" ::: "memory");
        __builtin_amdgcn_sched_barrier(0);
        __builtin_amdgcn_s_setprio(1);
#pragma unroll
        for (int mi = 0; mi < 4; ++mi)
#pragma unroll
            for (int n = 0; n < 4; ++n)
                acc[mi][n] = __builtin_amdgcn_mfma_f32_16x16x32_bf16(af[mi], bfr[n][1], acc[mi][n], 0, 0, 0);
        __builtin_amdgcn_s_setprio(0);
        __builtin_amdgcn_s_barrier();

        // ===== phase 2: mh=1, kk=0 — 4 ds_read; stage A{0,2}(t+2) =====
#pragma unroll
        for (int mi = 0; mi < 4; ++mi)
            af[mi] = *(const s16x8*)(AsF + aB + (arowb + (mi + 4) * 16) * BK + koffe0);
        if (t + 2 < NT) { STA(t + 2, b, 0); STA(t + 2, b, 2); }
        __builtin_amdgcn_s_barrier();
        asm volatile("s_waitcnt lgkmcnt(0)" ::: "memory");
        __builtin_amdgcn_sched_barrier(0);
        __builtin_amdgcn_s_setprio(1);
#pragma unroll
        for (int mi = 0; mi < 4; ++mi)
#pragma unroll
            for (int n = 0; n < 4; ++n)
                acc[mi + 4][n] = __builtin_amdgcn_mfma_f32_16x16x32_bf16(af[mi], bfr[n][0], acc[mi + 4][n], 0, 0, 0);
        __builtin_amdgcn_s_setprio(0);
        __builtin_amdgcn_s_barrier();

        // ===== phase 3: mh=1, kk=1 — 4 ds_read; counted vmcnt; stage B{0,1}(t+2) =====
#pragma unroll
        for (int mi = 0; mi < 4; ++mi)
            af[mi] = *(const s16x8*)(AsF + aB + (arowb + (mi + 4) * 16) * BK + koffe1);
        if (t + 2 < NT) {
            // outstanding: tile t+1's 8 (older) + A{0,2}(t+2) 2 (newer) -> drain t+1's
            asm volatile("s_waitcnt vmcnt(2)" ::: "memory");
            STB(t + 2, b, 0);
            STB(t + 2, b, 1);
        } else if (t + 1 < NT) {
            asm volatile("s_waitcnt vmcnt(0)" ::: "memory");  // drain tile t+1 (t == NT-2)
        }
        __builtin_amdgcn_s_barrier();
        asm volatile("s_waitcnt lgkmcnt(0)" ::: "memory");
        __builtin_amdgcn_sched_barrier(0);
        __builtin_amdgcn_s_setprio(1);
#pragma unroll
        for (int mi = 0; mi < 4; ++mi)
#pragma unroll
            for (int n = 0; n < 4; ++n)
                acc[mi + 4][n] = __builtin_amdgcn_mfma_f32_16x16x32_bf16(af[mi], bfr[n][1], acc[mi + 4][n], 0, 0, 0);
        __builtin_amdgcn_s_setprio(0);
        __builtin_amdgcn_s_barrier();
    }

    // epilogue: y = a_scale*w_scale[col]*acc + bias[col]; exact GELU
    float asc = a_scale[0];
    long long row0 = mrow0 + wr * 128;
    int colb = ncol0 + wc * 64 + (lane & 15);
    int rsubE = (lane >> 4) * 4;
#pragma unroll
    for (int n = 0; n < 4; ++n) {
        int col = colb + n * 16;
        float sc = asc * w_scale[col];
        float bz = bias[col];
#pragma unroll
        for (int m = 0; m < 8; ++m) {
            long long rb = row0 + m * 16 + rsubE;
#pragma unroll
            for (int rg = 0; rg < 4; ++rg) {
                long long rowi = rb + rg;
                if (rowi < M) {
                    float y = acc[m][n][rg] * sc + bz;
                    out[rowi * I_DIM + col] = 0.5f * y * (1.0f + erff(y * 0.70710678118654752f));
                }
            }
        }
    }
}

// ---- safety-net fallback (workspace too small): naive on-the-fly
__global__ void fallback_kernel(const float* __restrict__ x, const float* __restrict__ w,
                                const float* __restrict__ bias, const float* __restrict__ w_scale,
                                const float* __restrict__ w_zero, const float* __restrict__ a_scale,
                                const float* __restrict__ a_zero, float* __restrict__ out,
                                long long M) {
    long long gid = (long long)blockIdx.x * blockDim.x + threadIdx.x;
    if (gid >= M * I_DIM) return;
    int i = (int)(gid & (I_DIM - 1));
    long long row = gid >> 12;
    float as = a_scale[0], az = rintf(a_zero[0]);
    float wsc = w_scale[i], wz = rintf(w_zero[i]);
    const float* xr = x + row * K_DIM;
    const float* wrp = w + (long long)i * K_DIM;
    float accf = 0.0f;
    for (int k = 0; k < K_DIM; ++k)
        accf += fakeq_int(xr[k], as, az) * fakeq_int(wrp[k], wsc, wz);
    float y = accf * as * wsc + bias[i];
    out[gid] = 0.5f * y * (1.0f + erff(y * 0.70710678118654752f));
}

extern "C" void kernel_launch(void* const* d_in, const int* in_sizes, int n_in,
                              void* d_out, int out_size, void* d_ws, size_t ws_size,
                              hipStream_t stream) {
    const float* x       = (const float*)d_in[0];
    const float* w       = (const float*)d_in[1];
    const float* bias    = (const float*)d_in[2];
    const float* w_scale = (const float*)d_in[3];
    const float* w_zero  = (const float*)d_in[4];
    const float* a_scale = (const float*)d_in[5];
    const float* a_zero  = (const float*)d_in[6];
    float* out = (float*)d_out;

    long long n_x = in_sizes[0];  // M*K
    long long M = n_x / K_DIM;    // 12608
    size_t needA = (size_t)n_x * 2;
    size_t needW = (size_t)I_DIM * K_DIM * 2;

    if (ws_size >= needA + needW) {
        unsigned short* Aq = (unsigned short*)d_ws;
        unsigned short* Wq = (unsigned short*)((char*)d_ws + needA);

        long long blocksX = (n_x / 4 + 255) / 256;
        quant_x_kernel<<<(int)blocksX, 256, 0, stream>>>(x, Aq, a_scale, a_zero, n_x);

        long long ndw = (long long)I_DIM * K_DIM;
        long long blocksW = (ndw / 4 + 255) / 256;
        quant_w_kernel<<<(int)blocksW, 256, 0, stream>>>(w, Wq, w_scale, w_zero, ndw);

        int Mtiles = (int)((M + BM - 1) / BM);  // 50
        int Ntiles = I_DIM / BN;                // 16
        gemm_gelu_kernel<<<Mtiles * Ntiles, 512, 0, stream>>>(Aq, Wq, bias, w_scale, a_scale,
                                                              out, (int)M, Ntiles);
    } else {
        long long total = M * I_DIM;
        long long blocks = (total + 255) / 256;
        fallback_kernel<<<(int)blocks, 256, 0, stream>>>(x, w, bias, w_scale, w_zero,
                                                         a_scale, a_zero, out, M);
    }
}

// Round 3
// 203.494 us; speedup vs baseline: 1.2124x; 1.2124x over previous
//
#include <hip/hip_runtime.h>
#include <hip/hip_bf16.h>

typedef __attribute__((ext_vector_type(8))) short s16x8;
typedef __attribute__((ext_vector_type(4))) float f32x4;

#define K_DIM 1024
#define I_DIM 4096
#define BM 256
#define BN 256
#define BK 64
#define NT (K_DIM / BK)  // 16 K-tiles

__device__ __forceinline__ unsigned short f2bf_bits(float v) {
    // exact for integers |v| <= 255
    return (unsigned short)(__builtin_bit_cast(unsigned int, v) >> 16);
}

__device__ __forceinline__ float fakeq_int(float x, float s, float zp) {
    float q = fminf(fmaxf(rintf(x / s) + zp, 0.0f), 255.0f);
    return q - zp;
}

// ---- quantize activations: fp32 [M*K] -> bf16 integer codes (q - zp)
__global__ void quant_x_kernel(const float* __restrict__ x, unsigned short* __restrict__ Aq,
                               const float* __restrict__ a_scale, const float* __restrict__ a_zero,
                               long long n) {
    long long i = ((long long)blockIdx.x * blockDim.x + threadIdx.x) * 4;
    if (i >= n) return;
    float s = a_scale[0];
    float zp = rintf(a_zero[0]);
    float4 v = *(const float4*)(x + i);
    ushort4 o;
    o.x = f2bf_bits(fakeq_int(v.x, s, zp));
    o.y = f2bf_bits(fakeq_int(v.y, s, zp));
    o.z = f2bf_bits(fakeq_int(v.z, s, zp));
    o.w = f2bf_bits(fakeq_int(v.w, s, zp));
    *(ushort4*)(Aq + i) = o;
}

// ---- quantize weights: per-row scale/zero
__global__ void quant_w_kernel(const float* __restrict__ w, unsigned short* __restrict__ Wq,
                               const float* __restrict__ w_scale, const float* __restrict__ w_zero,
                               long long n) {
    long long i = ((long long)blockIdx.x * blockDim.x + threadIdx.x) * 4;
    if (i >= n) return;
    long long row = i >> 10;  // K = 1024
    float s = w_scale[row];
    float zp = rintf(w_zero[row]);
    float4 v = *(const float4*)(w + i);
    ushort4 o;
    o.x = f2bf_bits(fakeq_int(v.x, s, zp));
    o.y = f2bf_bits(fakeq_int(v.y, s, zp));
    o.z = f2bf_bits(fakeq_int(v.z, s, zp));
    o.w = f2bf_bits(fakeq_int(v.w, s, zp));
    *(ushort4*)(Wq + i) = o;
}

#define GLL(SRC, DST)                                                         \
    __builtin_amdgcn_global_load_lds(                                         \
        (const __attribute__((address_space(1))) void*)(SRC),                 \
        (__attribute__((address_space(3))) void*)(DST), 16, 0, 0)

// stage chunk CC (64 rows x 64 k) of K-tile TT into buffer BB
#define STA(TT, BB, CC) GLL(srcA[CC] + (TT) * BK, AsF + (BB) * (BM * BK) + (CC) * 4096 + wbase)
#define STB(TT, BB, CC) GLL(srcB[CC] + (TT) * BK, BsF + (BB) * (BN * BK) + (CC) * 4096 + wbase)

// ---- 256x256x64 phase-pipelined GEMM, fused scale+bias+exact GELU
__global__ __launch_bounds__(512, 2) void gemm_gelu_kernel(
    const unsigned short* __restrict__ Aq,   // [M][K] bf16 integer codes
    const unsigned short* __restrict__ Wq,   // [I][K]
    const float* __restrict__ bias,
    const float* __restrict__ w_scale,
    const float* __restrict__ a_scale,
    float* __restrict__ out,                 // [M][I] fp32
    int M, int Ntiles) {
    __shared__ alignas(16) unsigned short AsF[2 * BM * BK];  // 64 KB
    __shared__ alignas(16) unsigned short BsF[2 * BN * BK];  // 64 KB

    // bijective XCD-aware swizzle
    int nwg = gridDim.x, bid = blockIdx.x;
    int xcd = bid & 7, lin = bid >> 3;
    int q8 = nwg >> 3, r8 = nwg & 7;
    int swz = (xcd < r8 ? xcd * (q8 + 1) : r8 * (q8 + 1) + (xcd - r8) * q8) + lin;
    int mt = swz / Ntiles, nt = swz % Ntiles;

    int tid = threadIdx.x;
    int wave = tid >> 6, lane = tid & 63;
    int wr = wave >> 2, wc = wave & 3;  // 2 (M) x 4 (N) waves, per-wave 128x64

    long long mrow0 = (long long)mt * BM;
    int ncol0 = nt * BN;

    // staging: thread t covers row (chunk*64 + t>>3), source k-slot (t&7)^(row&7)
    int rsub = tid >> 3;
    int slotsrc = (tid & 7) ^ ((tid >> 3) & 7);
    const unsigned short* srcA[4];
    const unsigned short* srcB[4];
#pragma unroll
    for (int c = 0; c < 4; ++c) {
        long long ra = mrow0 + c * 64 + rsub;
        if (ra > (long long)M - 1) ra = M - 1;  // clamp: pad rows never stored
        srcA[c] = Aq + ra * K_DIM + slotsrc * 8;
        srcB[c] = Wq + ((long long)ncol0 + c * 64 + rsub) * K_DIM + slotsrc * 8;
    }
    int wbase = wave * 512;  // wave's 1KB slice of each 8KB chunk

    // ds_read: row = base + frag*16 + (lane&15); k-slot = ((lane>>4) + kk*4) ^ (lane&7)
    int s0 = (lane >> 4) ^ (lane & 7);
    int koffe0 = s0 * 8;
    int koffe1 = (s0 ^ 4) * 8;
    int arowb = wr * 128 + (lane & 15);
    int browb = wc * 64 + (lane & 15);

    f32x4 acc[8][4];
#pragma unroll
    for (int m = 0; m < 8; ++m)
#pragma unroll
        for (int n = 0; n < 4; ++n) acc[m][n] = (f32x4)0.0f;

    // prologue: tile0 full + tile1 {A0,A2,B0,B1}; leave tile1's 4 in flight
#pragma unroll
    for (int c = 0; c < 4; ++c) STA(0, 0, c);
#pragma unroll
    for (int c = 0; c < 4; ++c) STB(0, 0, c);
    STA(1, 1, 0);
    STA(1, 1, 2);
    STB(1, 1, 0);
    STB(1, 1, 1);
    asm volatile("s_waitcnt vmcnt(4)" ::: "memory");
    __builtin_amdgcn_s_barrier();

#pragma unroll 2
    for (int t = 0; t < NT; ++t) {
        const int b = t & 1, bn = b ^ 1;
        const int aB = b * (BM * BK), bB = b * (BN * BK);
        s16x8 af[4];
        s16x8 bfr[4][2];

        // ===== phase 0: mh=0, kk=0 — 8 ds_read; stage B{2,3}(t+1) =====
#pragma unroll
        for (int mi = 0; mi < 4; ++mi)
            af[mi] = *(const s16x8*)(AsF + aB + (arowb + mi * 16) * BK + koffe0);
#pragma unroll
        for (int n = 0; n < 4; ++n)
            bfr[n][0] = *(const s16x8*)(BsF + bB + (browb + n * 16) * BK + koffe0);
        if (t + 1 < NT) { STB(t + 1, bn, 2); STB(t + 1, bn, 3); }
        __builtin_amdgcn_s_barrier();
        asm volatile("s_waitcnt lgkmcnt(0)" ::: "memory");
        __builtin_amdgcn_s_setprio(1);
#pragma unroll
        for (int mi = 0; mi < 4; ++mi)
#pragma unroll
            for (int n = 0; n < 4; ++n)
                acc[mi][n] = __builtin_amdgcn_mfma_f32_16x16x32_bf16(af[mi], bfr[n][0], acc[mi][n], 0, 0, 0);
        __builtin_amdgcn_s_setprio(0);

        // ===== phase 1: mh=0, kk=1 — 8 ds_read; stage A{1,3}(t+1) =====
#pragma unroll
        for (int mi = 0; mi < 4; ++mi)
            af[mi] = *(const s16x8*)(AsF + aB + (arowb + mi * 16) * BK + koffe1);
#pragma unroll
        for (int n = 0; n < 4; ++n)
            bfr[n][1] = *(const s16x8*)(BsF + bB + (browb + n * 16) * BK + koffe1);
        if (t + 1 < NT) { STA(t + 1, bn, 1); STA(t + 1, bn, 3); }
        __builtin_amdgcn_s_barrier();
        asm volatile("s_waitcnt lgkmcnt(0)" ::: "memory");
        __builtin_amdgcn_s_setprio(1);
#pragma unroll
        for (int mi = 0; mi < 4; ++mi)
#pragma unroll
            for (int n = 0; n < 4; ++n)
                acc[mi][n] = __builtin_amdgcn_mfma_f32_16x16x32_bf16(af[mi], bfr[n][1], acc[mi][n], 0, 0, 0);
        __builtin_amdgcn_s_setprio(0);

        // ===== phase 2: mh=1, kk=0 — 4 ds_read; stage A{0,2}(t+2) =====
#pragma unroll
        for (int mi = 0; mi < 4; ++mi)
            af[mi] = *(const s16x8*)(AsF + aB + (arowb + (mi + 4) * 16) * BK + koffe0);
        if (t + 2 < NT) { STA(t + 2, b, 0); STA(t + 2, b, 2); }
        __builtin_amdgcn_s_barrier();
        asm volatile("s_waitcnt lgkmcnt(0)" ::: "memory");
        __builtin_amdgcn_s_setprio(1);
#pragma unroll
        for (int mi = 0; mi < 4; ++mi)
#pragma unroll
            for (int n = 0; n < 4; ++n)
                acc[mi + 4][n] = __builtin_amdgcn_mfma_f32_16x16x32_bf16(af[mi], bfr[n][0], acc[mi + 4][n], 0, 0, 0);
        __builtin_amdgcn_s_setprio(0);

        // ===== phase 3: mh=1, kk=1 — 4 ds_read; counted vmcnt; stage B{0,1}(t+2) =====
#pragma unroll
        for (int mi = 0; mi < 4; ++mi)
            af[mi] = *(const s16x8*)(AsF + aB + (arowb + (mi + 4) * 16) * BK + koffe1);
        if (t + 2 < NT) {
            // outstanding: tile t+1's 8 (older) + A{0,2}(t+2) 2 (newer) -> drain t+1's
            asm volatile("s_waitcnt vmcnt(2)" ::: "memory");
            STB(t + 2, b, 0);
            STB(t + 2, b, 1);
        } else if (t + 1 < NT) {
            asm volatile("s_waitcnt vmcnt(0)" ::: "memory");  // t == NT-2: drain tile t+1
        }
        __builtin_amdgcn_s_barrier();
        asm volatile("s_waitcnt lgkmcnt(0)" ::: "memory");
        __builtin_amdgcn_s_setprio(1);
#pragma unroll
        for (int mi = 0; mi < 4; ++mi)
#pragma unroll
            for (int n = 0; n < 4; ++n)
                acc[mi + 4][n] = __builtin_amdgcn_mfma_f32_16x16x32_bf16(af[mi], bfr[n][1], acc[mi + 4][n], 0, 0, 0);
        __builtin_amdgcn_s_setprio(0);
    }

    // epilogue: y = a_scale*w_scale[col]*acc + bias[col]; exact GELU
    float asc = a_scale[0];
    long long row0 = mrow0 + wr * 128;
    int colb = ncol0 + wc * 64 + (lane & 15);
    int rsubE = (lane >> 4) * 4;
    bool fullTile = (mrow0 + BM <= (long long)M);
    if (fullTile) {
#pragma unroll
        for (int n = 0; n < 4; ++n) {
            int col = colb + n * 16;
            float sc = asc * w_scale[col];
            float bz = bias[col];
#pragma unroll
            for (int m = 0; m < 8; ++m) {
                long long rb = row0 + m * 16 + rsubE;
#pragma unroll
                for (int rg = 0; rg < 4; ++rg) {
                    float y = acc[m][n][rg] * sc + bz;
                    out[(rb + rg) * I_DIM + col] = 0.5f * y * (1.0f + erff(y * 0.70710678118654752f));
                }
            }
        }
    } else {
#pragma unroll
        for (int n = 0; n < 4; ++n) {
            int col = colb + n * 16;
            float sc = asc * w_scale[col];
            float bz = bias[col];
#pragma unroll
            for (int m = 0; m < 8; ++m) {
                long long rb = row0 + m * 16 + rsubE;
#pragma unroll
                for (int rg = 0; rg < 4; ++rg) {
                    long long rowi = rb + rg;
                    if (rowi < M) {
                        float y = acc[m][n][rg] * sc + bz;
                        out[rowi * I_DIM + col] = 0.5f * y * (1.0f + erff(y * 0.70710678118654752f));
                    }
                }
            }
        }
    }
}

// ---- safety-net fallback (workspace too small): naive on-the-fly
__global__ void fallback_kernel(const float* __restrict__ x, const float* __restrict__ w,
                                const float* __restrict__ bias, const float* __restrict__ w_scale,
                                const float* __restrict__ w_zero, const float* __restrict__ a_scale,
                                const float* __restrict__ a_zero, float* __restrict__ out,
                                long long M) {
    long long gid = (long long)blockIdx.x * blockDim.x + threadIdx.x;
    if (gid >= M * I_DIM) return;
    int i = (int)(gid & (I_DIM - 1));
    long long row = gid >> 12;
    float as = a_scale[0], az = rintf(a_zero[0]);
    float wsc = w_scale[i], wz = rintf(w_zero[i]);
    const float* xr = x + row * K_DIM;
    const float* wrp = w + (long long)i * K_DIM;
    float accf = 0.0f;
    for (int k = 0; k < K_DIM; ++k)
        accf += fakeq_int(xr[k], as, az) * fakeq_int(wrp[k], wsc, wz);
    float y = accf * as * wsc + bias[i];
    out[gid] = 0.5f * y * (1.0f + erff(y * 0.70710678118654752f));
}

extern "C" void kernel_launch(void* const* d_in, const int* in_sizes, int n_in,
                              void* d_out, int out_size, void* d_ws, size_t ws_size,
                              hipStream_t stream) {
    const float* x       = (const float*)d_in[0];
    const float* w       = (const float*)d_in[1];
    const float* bias    = (const float*)d_in[2];
    const float* w_scale = (const float*)d_in[3];
    const float* w_zero  = (const float*)d_in[4];
    const float* a_scale = (const float*)d_in[5];
    const float* a_zero  = (const float*)d_in[6];
    float* out = (float*)d_out;

    long long n_x = in_sizes[0];  // M*K
    long long M = n_x / K_DIM;    // 12608
    size_t needA = (size_t)n_x * 2;
    size_t needW = (size_t)I_DIM * K_DIM * 2;

    if (ws_size >= needA + needW) {
        unsigned short* Aq = (unsigned short*)d_ws;
        unsigned short* Wq = (unsigned short*)((char*)d_ws + needA);

        long long blocksX = (n_x / 4 + 255) / 256;
        quant_x_kernel<<<(int)blocksX, 256, 0, stream>>>(x, Aq, a_scale, a_zero, n_x);

        long long ndw = (long long)I_DIM * K_DIM;
        long long blocksW = (ndw / 4 + 255) / 256;
        quant_w_kernel<<<(int)blocksW, 256, 0, stream>>>(w, Wq, w_scale, w_zero, ndw);

        int Mtiles = (int)((M + BM - 1) / BM);  // 50
        int Ntiles = I_DIM / BN;                // 16
        gemm_gelu_kernel<<<Mtiles * Ntiles, 512, 0, stream>>>(Aq, Wq, bias, w_scale, a_scale,
                                                              out, (int)M, Ntiles);
    } else {
        long long total = M * I_DIM;
        long long blocks = (total + 255) / 256;
        fallback_kernel<<<(int)blocks, 256, 0, stream>>>(x, w, bias, w_scale, w_zero,
                                                         a_scale, a_zero, out, M);
    }
}

// Round 4
// 183.269 us; speedup vs baseline: 1.3462x; 1.1104x over previous
//
#include <hip/hip_runtime.h>
#include <hip/hip_bf16.h>

typedef __attribute__((ext_vector_type(8))) short s16x8;
typedef __attribute__((ext_vector_type(4))) float f32x4;

#define K_DIM 1024
#define I_DIM 4096
#define BM 256
#define BN 256
#define BK 64
#define NT (K_DIM / BK)  // 16 K-tiles

__device__ __forceinline__ unsigned short f2bf_bits(float v) {
    // exact for integers |v| <= 255
    return (unsigned short)(__builtin_bit_cast(unsigned int, v) >> 16);
}

__device__ __forceinline__ float fakeq_int(float x, float s, float zp) {
    float q = fminf(fmaxf(rintf(x / s) + zp, 0.0f), 255.0f);
    return q - zp;
}

// branch-free tanh-GELU: y*sigmoid(2*c1*(y + c2*y^3)); |err vs exact| <= ~3e-4
__device__ __forceinline__ float gelu_tanh(float y) {
    float y2 = y * y;
    float z = y * fmaf(0.0356774081f, y2, 0.7978845608f);
    return y / (1.0f + __expf(-2.0f * z));
}

// ---- quantize activations: fp32 [M*K] -> bf16 integer codes (q - zp)
__global__ void quant_x_kernel(const float* __restrict__ x, unsigned short* __restrict__ Aq,
                               const float* __restrict__ a_scale, const float* __restrict__ a_zero,
                               long long n) {
    long long i = ((long long)blockIdx.x * blockDim.x + threadIdx.x) * 4;
    if (i >= n) return;
    float s = a_scale[0];
    float zp = rintf(a_zero[0]);
    float4 v = *(const float4*)(x + i);
    ushort4 o;
    o.x = f2bf_bits(fakeq_int(v.x, s, zp));
    o.y = f2bf_bits(fakeq_int(v.y, s, zp));
    o.z = f2bf_bits(fakeq_int(v.z, s, zp));
    o.w = f2bf_bits(fakeq_int(v.w, s, zp));
    *(ushort4*)(Aq + i) = o;
}

// ---- quantize weights: per-row scale/zero
__global__ void quant_w_kernel(const float* __restrict__ w, unsigned short* __restrict__ Wq,
                               const float* __restrict__ w_scale, const float* __restrict__ w_zero,
                               long long n) {
    long long i = ((long long)blockIdx.x * blockDim.x + threadIdx.x) * 4;
    if (i >= n) return;
    long long row = i >> 10;  // K = 1024
    float s = w_scale[row];
    float zp = rintf(w_zero[row]);
    float4 v = *(const float4*)(w + i);
    ushort4 o;
    o.x = f2bf_bits(fakeq_int(v.x, s, zp));
    o.y = f2bf_bits(fakeq_int(v.y, s, zp));
    o.z = f2bf_bits(fakeq_int(v.z, s, zp));
    o.w = f2bf_bits(fakeq_int(v.w, s, zp));
    *(ushort4*)(Wq + i) = o;
}

#define GLL(SRC, DST)                                                         \
    __builtin_amdgcn_global_load_lds(                                         \
        (const __attribute__((address_space(1))) void*)(SRC),                 \
        (__attribute__((address_space(3))) void*)(DST), 16, 0, 0)

// stage chunk CC (64 rows x 64 k) of K-tile TT into buffer BB
#define STA(TT, BB, CC) GLL(srcA[CC] + (TT) * BK, AsF + (BB) * (BM * BK) + (CC) * 4096 + wbase)
#define STB(TT, BB, CC) GLL(srcB[CC] + (TT) * BK, BsF + (BB) * (BN * BK) + (CC) * 4096 + wbase)

// ---- 256x256x64 8-phase GEMM (m201-faithful sync), fused scale+bias+GELU
__global__ __launch_bounds__(512, 2) void gemm_gelu_kernel(
    const unsigned short* __restrict__ Aq,   // [M][K] bf16 integer codes
    const unsigned short* __restrict__ Wq,   // [I][K]
    const float* __restrict__ bias,
    const float* __restrict__ w_scale,
    const float* __restrict__ a_scale,
    float* __restrict__ out,                 // [M][I] fp32
    int M, int Ntiles) {
    __shared__ alignas(16) unsigned short AsF[2 * BM * BK];  // 64 KB
    __shared__ alignas(16) unsigned short BsF[2 * BN * BK];  // 64 KB

    // bijective XCD-aware swizzle
    int nwg = gridDim.x, bid = blockIdx.x;
    int xcd = bid & 7, lin = bid >> 3;
    int q8 = nwg >> 3, r8 = nwg & 7;
    int swz = (xcd < r8 ? xcd * (q8 + 1) : r8 * (q8 + 1) + (xcd - r8) * q8) + lin;
    int mt = swz / Ntiles, nt = swz % Ntiles;

    int tid = threadIdx.x;
    int wave = tid >> 6, lane = tid & 63;
    int wr = wave >> 2, wc = wave & 3;  // 2 (M) x 4 (N) waves, per-wave 128x64

    long long mrow0 = (long long)mt * BM;
    int ncol0 = nt * BN;

    // staging: thread t covers row (chunk*64 + t>>3), source k-slot (t&7)^(row&7)
    int rsub = tid >> 3;
    int slotsrc = (tid & 7) ^ ((tid >> 3) & 7);
    const unsigned short* srcA[4];
    const unsigned short* srcB[4];
#pragma unroll
    for (int c = 0; c < 4; ++c) {
        long long ra = mrow0 + c * 64 + rsub;
        if (ra > (long long)M - 1) ra = M - 1;  // clamp: pad rows never stored
        srcA[c] = Aq + ra * K_DIM + slotsrc * 8;
        srcB[c] = Wq + ((long long)ncol0 + c * 64 + rsub) * K_DIM + slotsrc * 8;
    }
    int wbase = wave * 512;  // wave's 1KB slice of each 8KB chunk

    // ds_read: row = base + frag*16 + (lane&15); k-slot = ((lane>>4) + kk*4) ^ (lane&7)
    int s0 = (lane >> 4) ^ (lane & 7);
    int koffe0 = s0 * 8;
    int koffe1 = (s0 ^ 4) * 8;
    int arowb = wr * 128 + (lane & 15);
    int browb = wc * 64 + (lane & 15);

    f32x4 acc[8][4];
#pragma unroll
    for (int m = 0; m < 8; ++m)
#pragma unroll
        for (int n = 0; n < 4; ++n) acc[m][n] = (f32x4)0.0f;

    // prologue: tile0 full + tile1 {A0,A2,B0,B1}; leave tile1's 4 in flight
#pragma unroll
    for (int c = 0; c < 4; ++c) STA(0, 0, c);
#pragma unroll
    for (int c = 0; c < 4; ++c) STB(0, 0, c);
    STA(1, 1, 0);
    STA(1, 1, 2);
    STB(1, 1, 0);
    STB(1, 1, 1);
    asm volatile("s_waitcnt vmcnt(4)" ::: "memory");
    __builtin_amdgcn_s_barrier();

#pragma unroll 2
    for (int t = 0; t < NT; ++t) {
        const int b = t & 1, bn = b ^ 1;
        const int aB = b * (BM * BK), bB = b * (BN * BK);
        s16x8 af[4];
        s16x8 bfr[4][2];

        // ===== phase 0: mh=0, kk=0 — 8 ds_read; stage B{2,3}(t+1) =====
#pragma unroll
        for (int mi = 0; mi < 4; ++mi)
            af[mi] = *(const s16x8*)(AsF + aB + (arowb + mi * 16) * BK + koffe0);
#pragma unroll
        for (int n = 0; n < 4; ++n)
            bfr[n][0] = *(const s16x8*)(BsF + bB + (browb + n * 16) * BK + koffe0);
        if (t + 1 < NT) { STB(t + 1, bn, 2); STB(t + 1, bn, 3); }
        __builtin_amdgcn_s_barrier();
        asm volatile("s_waitcnt lgkmcnt(0)" ::: "memory");
        __builtin_amdgcn_s_setprio(1);
#pragma unroll
        for (int mi = 0; mi < 4; ++mi)
#pragma unroll
            for (int n = 0; n < 4; ++n)
                acc[mi][n] = __builtin_amdgcn_mfma_f32_16x16x32_bf16(af[mi], bfr[n][0], acc[mi][n], 0, 0, 0);
        __builtin_amdgcn_s_setprio(0);
        __builtin_amdgcn_s_barrier();

        // ===== phase 1: mh=0, kk=1 — 8 ds_read; stage A{1,3}(t+1) =====
#pragma unroll
        for (int mi = 0; mi < 4; ++mi)
            af[mi] = *(const s16x8*)(AsF + aB + (arowb + mi * 16) * BK + koffe1);
#pragma unroll
        for (int n = 0; n < 4; ++n)
            bfr[n][1] = *(const s16x8*)(BsF + bB + (browb + n * 16) * BK + koffe1);
        if (t + 1 < NT) { STA(t + 1, bn, 1); STA(t + 1, bn, 3); }
        __builtin_amdgcn_s_barrier();
        asm volatile("s_waitcnt lgkmcnt(0)" ::: "memory");
        __builtin_amdgcn_s_setprio(1);
#pragma unroll
        for (int mi = 0; mi < 4; ++mi)
#pragma unroll
            for (int n = 0; n < 4; ++n)
                acc[mi][n] = __builtin_amdgcn_mfma_f32_16x16x32_bf16(af[mi], bfr[n][1], acc[mi][n], 0, 0, 0);
        __builtin_amdgcn_s_setprio(0);
        __builtin_amdgcn_s_barrier();

        // ===== phase 2: mh=1, kk=0 — 4 ds_read; stage A{0,2}(t+2) =====
#pragma unroll
        for (int mi = 0; mi < 4; ++mi)
            af[mi] = *(const s16x8*)(AsF + aB + (arowb + (mi + 4) * 16) * BK + koffe0);
        if (t + 2 < NT) { STA(t + 2, b, 0); STA(t + 2, b, 2); }
        __builtin_amdgcn_s_barrier();
        asm volatile("s_waitcnt lgkmcnt(0)" ::: "memory");
        __builtin_amdgcn_s_setprio(1);
#pragma unroll
        for (int mi = 0; mi < 4; ++mi)
#pragma unroll
            for (int n = 0; n < 4; ++n)
                acc[mi + 4][n] = __builtin_amdgcn_mfma_f32_16x16x32_bf16(af[mi], bfr[n][0], acc[mi + 4][n], 0, 0, 0);
        __builtin_amdgcn_s_setprio(0);
        __builtin_amdgcn_s_barrier();

        // ===== phase 3: mh=1, kk=1 — 4 ds_read; counted vmcnt; stage B{0,1}(t+2) =====
#pragma unroll
        for (int mi = 0; mi < 4; ++mi)
            af[mi] = *(const s16x8*)(AsF + aB + (arowb + (mi + 4) * 16) * BK + koffe1);
        if (t + 2 < NT) {
            // outstanding: tile t+1's 8 (older) + A{0,2}(t+2) 2 (newer) -> drain t+1's
            asm volatile("s_waitcnt vmcnt(2)" ::: "memory");
            STB(t + 2, b, 0);
            STB(t + 2, b, 1);
        } else if (t + 1 < NT) {
            asm volatile("s_waitcnt vmcnt(0)" ::: "memory");  // t == NT-2: drain tile t+1
        }
        __builtin_amdgcn_s_barrier();
        asm volatile("s_waitcnt lgkmcnt(0)" ::: "memory");
        __builtin_amdgcn_s_setprio(1);
#pragma unroll
        for (int mi = 0; mi < 4; ++mi)
#pragma unroll
            for (int n = 0; n < 4; ++n)
                acc[mi + 4][n] = __builtin_amdgcn_mfma_f32_16x16x32_bf16(af[mi], bfr[n][1], acc[mi + 4][n], 0, 0, 0);
        __builtin_amdgcn_s_setprio(0);
        __builtin_amdgcn_s_barrier();
    }

    // epilogue: y = a_scale*w_scale[col]*acc + bias[col]; tanh-GELU
    float asc = a_scale[0];
    long long row0 = mrow0 + wr * 128;
    int colb = ncol0 + wc * 64 + (lane & 15);
    int rsubE = (lane >> 4) * 4;
    bool fullTile = (mrow0 + BM <= (long long)M);
    if (fullTile) {
#pragma unroll
        for (int n = 0; n < 4; ++n) {
            int col = colb + n * 16;
            float sc = asc * w_scale[col];
            float bz = bias[col];
#pragma unroll
            for (int m = 0; m < 8; ++m) {
                long long rb = row0 + m * 16 + rsubE;
#pragma unroll
                for (int rg = 0; rg < 4; ++rg) {
                    float y = acc[m][n][rg] * sc + bz;
                    out[(rb + rg) * I_DIM + col] = gelu_tanh(y);
                }
            }
        }
    } else {
#pragma unroll
        for (int n = 0; n < 4; ++n) {
            int col = colb + n * 16;
            float sc = asc * w_scale[col];
            float bz = bias[col];
#pragma unroll
            for (int m = 0; m < 8; ++m) {
                long long rb = row0 + m * 16 + rsubE;
#pragma unroll
                for (int rg = 0; rg < 4; ++rg) {
                    long long rowi = rb + rg;
                    if (rowi < M) {
                        float y = acc[m][n][rg] * sc + bz;
                        out[rowi * I_DIM + col] = gelu_tanh(y);
                    }
                }
            }
        }
    }
}

// ---- safety-net fallback (workspace too small): naive on-the-fly
__global__ void fallback_kernel(const float* __restrict__ x, const float* __restrict__ w,
                                const float* __restrict__ bias, const float* __restrict__ w_scale,
                                const float* __restrict__ w_zero, const float* __restrict__ a_scale,
                                const float* __restrict__ a_zero, float* __restrict__ out,
                                long long M) {
    long long gid = (long long)blockIdx.x * blockDim.x + threadIdx.x;
    if (gid >= M * I_DIM) return;
    int i = (int)(gid & (I_DIM - 1));
    long long row = gid >> 12;
    float as = a_scale[0], az = rintf(a_zero[0]);
    float wsc = w_scale[i], wz = rintf(w_zero[i]);
    const float* xr = x + row * K_DIM;
    const float* wrp = w + (long long)i * K_DIM;
    float accf = 0.0f;
    for (int k = 0; k < K_DIM; ++k)
        accf += fakeq_int(xr[k], as, az) * fakeq_int(wrp[k], wsc, wz);
    float y = accf * as * wsc + bias[i];
    out[gid] = 0.5f * y * (1.0f + erff(y * 0.70710678118654752f));
}

extern "C" void kernel_launch(void* const* d_in, const int* in_sizes, int n_in,
                              void* d_out, int out_size, void* d_ws, size_t ws_size,
                              hipStream_t stream) {
    const float* x       = (const float*)d_in[0];
    const float* w       = (const float*)d_in[1];
    const float* bias    = (const float*)d_in[2];
    const float* w_scale = (const float*)d_in[3];
    const float* w_zero  = (const float*)d_in[4];
    const float* a_scale = (const float*)d_in[5];
    const float* a_zero  = (const float*)d_in[6];
    float* out = (float*)d_out;

    long long n_x = in_sizes[0];  // M*K
    long long M = n_x / K_DIM;    // 12608
    size_t needA = (size_t)n_x * 2;
    size_t needW = (size_t)I_DIM * K_DIM * 2;

    if (ws_size >= needA + needW) {
        unsigned short* Aq = (unsigned short*)d_ws;
        unsigned short* Wq = (unsigned short*)((char*)d_ws + needA);

        long long blocksX = (n_x / 4 + 255) / 256;
        quant_x_kernel<<<(int)blocksX, 256, 0, stream>>>(x, Aq, a_scale, a_zero, n_x);

        long long ndw = (long long)I_DIM * K_DIM;
        long long blocksW = (ndw / 4 + 255) / 256;
        quant_w_kernel<<<(int)blocksW, 256, 0, stream>>>(w, Wq, w_scale, w_zero, ndw);

        int Mtiles = (int)((M + BM - 1) / BM);  // 50
        int Ntiles = I_DIM / BN;                // 16
        gemm_gelu_kernel<<<Mtiles * Ntiles, 512, 0, stream>>>(Aq, Wq, bias, w_scale, a_scale,
                                                              out, (int)M, Ntiles);
    } else {
        long long total = M * I_DIM;
        long long blocks = (total + 255) / 256;
        fallback_kernel<<<(int)blocks, 256, 0, stream>>>(x, w, bias, w_scale, w_zero,
                                                         a_scale, a_zero, out, M);
    }
}